// Round 12
// baseline (187.898 us; speedup 1.0000x reference)
//
#include <hip/hip_runtime.h>
#include <hip/hip_bf16.h>

// AAConv2d: B=8, CIN=128, H=W=32, COUT=128, K=3, DK=DV=64, NH=8, dkh=dvh=8
// out[:, 0:64]  = conv3x3(x, w_general) + b_general
// out[:, 64:128]= conv3x3(attn_combined, w_out) + b_out
// Rel logits (verified): logits[n,m] += dot(q[:, m>>5, n>>5], krw[(m&31)-(m>>5)+31])
//                                    + dot(q[:, m>>5, n>>5], krh[(n&31)-(n>>5)+31])
// flat_q/flat_k/flat_v are RAW reshapes: row n = linear elements n*8..n*8+7 of
// the channel-major (8,1024) head block (R11 lesson: do NOT transpose k/v).
// dtype detected at runtime (fp32 in practice). attention: fp32 q x bf16 k/v
// (raw layout), packed f32x2 math; 3x3 convs: bf16 MFMA implicit GEMM.

#define NP 1024
#define QSCALE 2.8284271247461903f   // q / (8^-0.5) = q*sqrt(8)
#define LOG2E  1.4426950408889634f

using bf16 = __hip_bfloat16;
typedef unsigned short ushort;
typedef unsigned int uint;
using bf16x8 = __attribute__((ext_vector_type(8))) short;  // 8 bf16 = 4 VGPRs
using f32x4  = __attribute__((ext_vector_type(4))) float;
using f32x2  = __attribute__((ext_vector_type(2))) float;

__device__ __forceinline__ float b2f(bf16 v) { return __bfloat162float(v); }
__device__ __forceinline__ ushort f2b(float v) {
  bf16 h = __float2bfloat16(v);
  ushort u; __builtin_memcpy(&u, &h, 2); return u;
}
__device__ __forceinline__ f32x2 up2(uint u) {   // 2 packed bf16 -> 2 f32
  f32x2 r;
  r[0] = __uint_as_float(u << 16);
  r[1] = __uint_as_float(u & 0xffff0000u);
  return r;
}

__device__ __forceinline__ float dot8(const float* a, const float* b) {
  float s = a[0] * b[0];
  s = fmaf(a[1], b[1], s); s = fmaf(a[2], b[2], s); s = fmaf(a[3], b[3], s);
  s = fmaf(a[4], b[4], s); s = fmaf(a[5], b[5], s); s = fmaf(a[6], b[6], s);
  s = fmaf(a[7], b[7], s);
  return s;
}

__device__ __forceinline__ int fenc(float f) { int i = __float_as_int(f); return i < 0 ? (i ^ 0x7fffffff) : i; }
__device__ __forceinline__ float fdec(int i) { return __int_as_float(i < 0 ? (i ^ 0x7fffffff) : i); }

#if defined(__has_builtin)
#if __has_builtin(__builtin_amdgcn_exp2f)
#define EXP2F __builtin_amdgcn_exp2f
#else
#define EXP2F exp2f
#endif
#else
#define EXP2F exp2f
#endif

// ---- workspace float offsets ----------------------------------------------
#define OFF_QBUF   0          // f32 [8][64][1024]
#define OFF_KB16   524288     // ushort[8][64][1024] raw channel-major bf16
#define OFF_VB16   786432     // ushort[8][64][1024]
#define OFF_XPB    1048576    // ushort[8][34][34][128] (591872 floats)
#define OFF_APB    1640448    // ushort[8][34][34][64]  (295936 floats)
#define OFF_WGB    1936384    // ushort[9][64][128]
#define OFF_WOB    1973248    // ushort[9][64][64]
#define OFF_BG     1991680
#define OFF_BQKV   1991744
#define OFF_BO     1991936
#define OFF_KRH    1992000
#define OFF_KRW    1992504
#define OFF_FLAG   1993016

// ---------------------------------------------------------------------------
// Kernel 0: dtype detect + small fp32 copies + HALO-only zeroing of padded
// buffers + weight bf16 transforms + (blocks<128) x->xpb bf16 transpose.
// ---------------------------------------------------------------------------
__global__ __launch_bounds__(256) void cvt_kernel(
    const void* __restrict__ p0, const void* __restrict__ p1, const void* __restrict__ p2,
    const void* __restrict__ p3, const void* __restrict__ p4, const void* __restrict__ p5,
    const void* __restrict__ p6, const void* __restrict__ p7, const void* __restrict__ p8,
    float* __restrict__ ws, int* __restrict__ flag)
{
  __shared__ int partial[4];
  __shared__ uint lds[64][65];
  int t = threadIdx.x;
  const unsigned* xraw = (const unsigned*)p0;
  int cnt = 0;
  for (int i = t; i < 1024; i += 256) {
    unsigned elo = (xraw[i] >> 7) & 0xffu;
    cnt += (elo >= 64u && elo <= 133u) ? 1 : 0;
  }
#pragma unroll
  for (int off = 1; off < 64; off <<= 1) cnt += __shfl_xor(cnt, off);
  if ((t & 63) == 0) partial[t >> 6] = cnt;
  __syncthreads();
  int tot = partial[0] + partial[1] + partial[2] + partial[3];
  int f32 = (tot >= 650) ? 0 : 1;   // 1 = fp32 tensors, 0 = bf16 tensors
  if (blockIdx.x == 0 && t == 0) *flag = f32;

  int gsz = gridDim.x * 256;
  int gid = blockIdx.x * 256 + t;

  // small fp32 copies (bg, bqkv, bo, krh, krw)
  const void* src[5] = {p2, p4, p6, p7, p8};
  const int   n[5]    = {64, 192, 64, 504, 504};
  const int   doff[5] = {OFF_BG, OFF_BQKV, OFF_BO, OFF_KRH, OFF_KRW};
#pragma unroll
  for (int s = 0; s < 5; s++) {
    float* dst = ws + doff[s];
    if (f32) { const float* sp = (const float*)src[s];
      for (int i = gid; i < n[s]; i += gsz) dst[i] = sp[i];
    } else { const bf16* sp = (const bf16*)src[s];
      for (int i = gid; i < n[s]; i += gsz) dst[i] = b2f(sp[i]);
    }
  }

  // halo zeroing: xpb (16 uint4/px), apb (8 uint4/px)
  {
    uint4 z = {0u, 0u, 0u, 0u};
    uint4* xp = (uint4*)(ws + OFF_XPB);
    uint4* ap = (uint4*)(ws + OFF_APB);
    for (int s = gid; s < 9248; s += gsz) {
      int pb = s / 1156, rem = s - pb * 1156;
      int y = rem / 34, x = rem - y * 34;
      if (y == 0 || y == 33 || x == 0 || x == 33) {
        uint4* d1 = xp + (size_t)s * 16;
#pragma unroll
        for (int k = 0; k < 16; k++) d1[k] = z;
        uint4* d2 = ap + (size_t)s * 8;
#pragma unroll
        for (int k = 0; k < 8; k++) d2[k] = z;
      }
    }
  }

  // w_general -> wgb bf16 [kykx][co][ci]
  {
    ushort* wgb = (ushort*)(ws + OFF_WGB);
    for (int s = gid; s < 73728; s += gsz) {
      int kykx = s >> 13, co = (s >> 7) & 63, ci = s & 127;
      int si = (co * 128 + ci) * 9 + kykx;
      wgb[s] = f32 ? f2b(((const float*)p1)[si]) : ((const ushort*)p1)[si];
    }
  }
  // w_out -> wob bf16 [kykx][co][ci]
  {
    ushort* wob = (ushort*)(ws + OFF_WOB);
    for (int s = gid; s < 36864; s += gsz) {
      int kykx = s >> 12, co = (s >> 6) & 63, ci = s & 63;
      int si = (co * 64 + ci) * 9 + kykx;
      wob[s] = f32 ? f2b(((const float*)p5)[si]) : ((const ushort*)p5)[si];
    }
  }

  // x -> xpb interior transpose (blocks 0..127): 64 px x 128 ci per block
  if (blockIdx.x < 128) {
    int w = t >> 6, lane = t & 63;
    int b = blockIdx.x >> 4;
    int pp0 = (blockIdx.x & 15) * 64;
    if (f32) {
      const float* xs = (const float*)p0 + (size_t)b * 131072 + pp0;
#pragma unroll 4
      for (int i = 0; i < 16; i++) {
        int cp = w * 16 + i;
        float v0 = xs[(size_t)(2 * cp) * 1024 + lane];
        float v1 = xs[(size_t)(2 * cp + 1) * 1024 + lane];
        lds[cp][lane] = (uint)f2b(v0) | ((uint)f2b(v1) << 16);
      }
    } else {
      const ushort* xs = (const ushort*)p0 + (size_t)b * 131072 + pp0;
#pragma unroll 4
      for (int i = 0; i < 16; i++) {
        int cp = w * 16 + i;
        uint v0 = xs[(size_t)(2 * cp) * 1024 + lane];
        uint v1 = xs[(size_t)(2 * cp + 1) * 1024 + lane];
        lds[cp][lane] = v0 | (v1 << 16);
      }
    }
    __syncthreads();
    uint* xp32 = (uint*)(ws + OFF_XPB);
#pragma unroll 4
    for (int i = 0; i < 16; i++) {
      int p = w * 16 + i;
      int pp = pp0 + p;
      int y = pp >> 5, x = pp & 31;
      xp32[((size_t)(b * 34 + y + 1) * 34 + x + 1) * 64 + lane] = lds[lane][p];
    }
  }
}

// ---------------------------------------------------------------------------
// Kernel 1: qkv 1x1 conv. grid (b=8, pg=16, cog=6) = 768 blocks.
// q (cog 0,1): fp32 scaled, layout [b][ch][px].
// k (cog 2,3) / v (cog 4,5): bf16 RAW channel-major [b][64ch][1024px] —
// simple px-pair pack, no transpose (flat_k row m = linear elems m*8..m*8+7).
// ---------------------------------------------------------------------------
__global__ __launch_bounds__(256) void qkv_kernel(
    const void* __restrict__ xin, const void* __restrict__ wraw, const float* __restrict__ bias,
    float* __restrict__ qbuf, ushort* __restrict__ kb16, ushort* __restrict__ vb16,
    const int* __restrict__ flag)
{
  __shared__ float xt[128][64];   // 32 KB
  __shared__ float wt[128][36];   // 18 KB
  int b = blockIdx.x, pg = blockIdx.y, cog = blockIdx.z;
  int t = threadIdx.x;
  int p0 = pg * 64;
  int f32 = *flag;
  if (f32) {
    const float* xs = (const float*)xin + (size_t)b * 131072;
    for (int idx = t; idx < 8192; idx += 256) {
      int ci = idx >> 6, p = idx & 63;
      xt[ci][p] = xs[ci * 1024 + p0 + p];
    }
    const float* wsrc = (const float*)wraw;
    for (int idx = t; idx < 4096; idx += 256) {
      int co = idx >> 7, ci = idx & 127;
      wt[ci][co] = wsrc[(cog * 32 + co) * 128 + ci];
    }
  } else {
    const bf16* xs = (const bf16*)xin + (size_t)b * 131072;
    for (int idx = t; idx < 8192; idx += 256) {
      int ci = idx >> 6, p = idx & 63;
      xt[ci][p] = b2f(xs[ci * 1024 + p0 + p]);
    }
    const bf16* wsrc = (const bf16*)wraw;
    for (int idx = t; idx < 4096; idx += 256) {
      int co = idx >> 7, ci = idx & 127;
      wt[ci][co] = b2f(wsrc[(cog * 32 + co) * 128 + ci]);
    }
  }
  __syncthreads();

  int cog2 = t >> 5;        // 0..7 -> 4 co each
  int pl = (t & 31) * 2;    // px pair
  float a0[4] = {0.f, 0.f, 0.f, 0.f};
  float a1[4] = {0.f, 0.f, 0.f, 0.f};
  for (int ci = 0; ci < 128; ci++) {
    float2 xv = *(const float2*)&xt[ci][pl];
    float4 wv = *(const float4*)&wt[ci][cog2 * 4];
    a0[0] = fmaf(xv.x, wv.x, a0[0]); a1[0] = fmaf(xv.y, wv.x, a1[0]);
    a0[1] = fmaf(xv.x, wv.y, a0[1]); a1[1] = fmaf(xv.y, wv.y, a1[1]);
    a0[2] = fmaf(xv.x, wv.z, a0[2]); a1[2] = fmaf(xv.y, wv.z, a1[2]);
    a0[3] = fmaf(xv.x, wv.w, a0[3]); a1[3] = fmaf(xv.y, wv.w, a1[3]);
  }

  if (cog < 2) {
#pragma unroll
    for (int j = 0; j < 4; j++) {
      int co = cog * 32 + cog2 * 4 + j;
      float bv = bias[co];
      float2 pk; pk.x = (a0[j] + bv) * QSCALE; pk.y = (a1[j] + bv) * QSCALE;
      *(float2*)(qbuf + ((size_t)b * 64 + co) * NP + p0 + pl) = pk;
    }
  } else {
    uint* dstb = (uint*)((cog < 4) ? kb16 : vb16);
    int chbase = (cog & 1) * 32;   // cog 2/4 -> ch 0..31, cog 3/5 -> ch 32..63
#pragma unroll
    for (int j = 0; j < 4; j++) {
      int co = cog * 32 + cog2 * 4 + j;
      int ch = chbase + cog2 * 4 + j;
      float bv = bias[co];
      uint u = (uint)f2b(a0[j] + bv) | ((uint)f2b(a1[j] + bv) << 16);
      dstb[(((size_t)b * 64 + ch) * NP + p0 + pl) >> 1] = u;
    }
  }
}

// ---------------------------------------------------------------------------
// Kernel 2: attention. fp32 q (pre-scaled by log2e) x bf16 k/v raw streams
// (32 B/thread/iter), packed f32x2 fma. Single-pass upper-bound softmax,
// phase-split rows, ~22.5 KB LDS.
// ---------------------------------------------------------------------------
__global__ __launch_bounds__(256, 4) void attn_kernel(
    const float* __restrict__ qbuf, const ushort* __restrict__ kb16, const ushort* __restrict__ vb16,
    const float* __restrict__ krh, const float* __restrict__ krw,
    ushort* __restrict__ apb)
{
  __shared__ float bw2[2][NP];
  __shared__ float bhT[2][32][32];
  __shared__ float qsT[2][32][8];
  __shared__ float krhs[64][8];
  __shared__ float krws[64][8];
  __shared__ int smax[3];

  int t = threadIdx.x;
  int cp = blockIdx.x, h = blockIdx.y, b = blockIdx.z;
  int C0 = cp * 2;
  const float* qbase = qbuf + ((size_t)b * 64 + h * 8) * NP;
  // raw head block: 8192 consecutive bf16 = 1024 flat rows x 8
  const uint4* kb4 = (const uint4*)(kb16 + ((size_t)b * 64 + h * 8) * NP);
  const uint4* vb4 = (const uint4*)(vb16 + ((size_t)b * 64 + h * 8) * NP);

  if (t < 3) smax[t] = (t == 0) ? 0 : fenc(-3.0e38f);

  for (int idx = t; idx < 63 * 8; idx += 256) {
    krhs[idx >> 3][idx & 7] = krh[idx];
    krws[idx >> 3][idx & 7] = krw[idx];
  }
  for (int idx = t; idx < 512; idx += 256) {
    int cs = idx >> 8, d = (idx >> 5) & 7, r = idx & 31;
    qsT[cs][r][d] = qbase[(size_t)d * NP + r * 32 + (C0 + cs)];
  }
  // scan bf16 flat_k rows for max ||k_m||^2
  float kn2 = 0.f;
#pragma unroll
  for (int rr = 0; rr < 4; rr++) {
    uint4 ku = kb4[rr * 256 + t];
    f32x2 k0 = up2(ku.x), k1 = up2(ku.y), k2 = up2(ku.z), k3 = up2(ku.w);
    f32x2 s2 = k0 * k0;
    s2 = __builtin_elementwise_fma(k1, k1, s2);
    s2 = __builtin_elementwise_fma(k2, k2, s2);
    s2 = __builtin_elementwise_fma(k3, k3, s2);
    kn2 = fmaxf(kn2, s2[0] + s2[1]);
  }
  __syncthreads();
  atomicMax(&smax[0], __float_as_int(kn2));

  float bwm = -3.0e38f;
  for (int idx = t; idx < 2048; idx += 256) {
    int cs = idx >> 10, m = idx & 1023;
    int rg = m >> 5, j2 = m & 31;
    float s = dot8(qsT[cs][rg], krws[j2 - rg + 31]) * LOG2E;
    bw2[cs][m] = s;
    bwm = fmaxf(bwm, s);
  }
  float bhm = -3.0e38f;
  for (int idx = t; idx < 2048; idx += 256) {
    int cs = idx >> 10, r = idx & 1023;
    int i = r >> 5, J = r & 31;
    float s = dot8(qsT[cs][i], krhs[J - (C0 + cs) + 31]) * LOG2E;
    bhT[cs][i][J] = s;
    bhm = fmaxf(bhm, s);
  }
  atomicMax(&smax[1], fenc(bwm));
  atomicMax(&smax[2], fenc(bhm));
  __syncthreads();

  float kmaxn = sqrtf(__int_as_float(smax[0]));
  float bmax = fdec(smax[1]) + fdec(smax[2]);

  int Csub = t >> 7, rowg = (t >> 5) & 3, seg = t & 31;
  int C = C0 + Csub;
  const float* bwX = bw2[Csub];
  const float* qrowbase = qbase + (size_t)C * 256 + rowg * 64;

#pragma unroll 1
  for (int ph = 0; ph < 2; ph++) {
    const float* qrow = qrowbase + ph * 32;
    f32x2 q2[4][4], O2[4][4];
    float M[4], l[4];
#pragma unroll
    for (int r = 0; r < 4; r++) {
      float nn = 0.f;
#pragma unroll
      for (int j = 0; j < 4; j++) {
        float va = qrow[r * 8 + 2 * j] * LOG2E;
        float vb2 = qrow[r * 8 + 2 * j + 1] * LOG2E;
        f32x2 qq; qq[0] = va; qq[1] = vb2;
        q2[r][j] = qq;
        nn = fmaf(va, va, fmaf(vb2, vb2, nn));
        f32x2 zz; zz[0] = 0.f; zz[1] = 0.f;
        O2[r][j] = zz;
      }
      M[r] = sqrtf(nn) * kmaxn + bmax;   // safe scaled-domain upper bound
      l[r] = 0.f;
    }

    for (int i = 0; i < 32; ++i) {
      int m = i * 32 + seg;
      uint4 ku = kb4[m];
      uint4 vu = vb4[m];
      f32x2 k0 = up2(ku.x), k1 = up2(ku.y), k2 = up2(ku.z), k3 = up2(ku.w);
      f32x2 v0 = up2(vu.x), v1 = up2(vu.y), v2 = up2(vu.z), v3 = up2(vu.w);
      float bwv = bwX[m];
      float4 bh4 = *(const float4*)&bhT[Csub][i][rowg * 8 + ph * 4];
      float cr[4] = {bh4.x, bh4.y, bh4.z, bh4.w};
#pragma unroll
      for (int r = 0; r < 4; ++r) {
        f32x2 s2; s2[0] = bwv + (cr[r] - M[r]); s2[1] = 0.f;
        s2 = __builtin_elementwise_fma(q2[r][0], k0, s2);
        s2 = __builtin_elementwise_fma(q2[r][1], k1, s2);
        s2 = __builtin_elementwise_fma(q2[r][2], k2, s2);
        s2 = __builtin_elementwise_fma(q2[r][3], k3, s2);
        float p = EXP2F(s2[0] + s2[1]);
        l[r] += p;
        f32x2 p2; p2[0] = p; p2[1] = p;
        O2[r][0] = __builtin_elementwise_fma(p2, v0, O2[r][0]);
        O2[r][1] = __builtin_elementwise_fma(p2, v1, O2[r][1]);
        O2[r][2] = __builtin_elementwise_fma(p2, v2, O2[r][2]);
        O2[r][3] = __builtin_elementwise_fma(p2, v3, O2[r][3]);
      }
    }

    // reduce over the 32 segment lanes (xor < 32 stays in 32-lane halves)
#pragma unroll
    for (int off = 1; off < 32; off <<= 1) {
#pragma unroll
      for (int r = 0; r < 4; r++) {
        l[r] += __shfl_xor(l[r], off);
#pragma unroll
        for (int j = 0; j < 4; j++) {
          O2[r][j][0] += __shfl_xor(O2[r][j][0], off);
          O2[r][j][1] += __shfl_xor(O2[r][j][1], off);
        }
      }
    }
    if (seg == 0) {
#pragma unroll
      for (int r = 0; r < 4; r++) {
        float inv = 1.f / l[r];
        int n = C * 32 + rowg * 8 + ph * 4 + r;
        int yy = (n >> 5) + 1, xx = (n & 31) + 1;
        ushort u[8];
#pragma unroll
        for (int j = 0; j < 4; j++) {
          u[2 * j] = f2b(O2[r][j][0] * inv);
          u[2 * j + 1] = f2b(O2[r][j][1] * inv);
        }
        uint4 pk;
        pk.x = (uint)u[0] | ((uint)u[1] << 16);
        pk.y = (uint)u[2] | ((uint)u[3] << 16);
        pk.z = (uint)u[4] | ((uint)u[5] << 16);
        pk.w = (uint)u[6] | ((uint)u[7] << 16);
        *(uint4*)(apb + ((size_t)(b * 34 + yy) * 34 + xx) * 64 + h * 8) = pk;
      }
    }
  }
}

// ---------------------------------------------------------------------------
// Kernel 3: conv3x3 as bf16 MFMA implicit GEMM; dual acc chains.
// grid (pxtile=64, b=8) = 512 blocks.
// ---------------------------------------------------------------------------
template <int CINT>
__global__ __launch_bounds__(256) void conv_mfma_kernel(
    const ushort* __restrict__ xp, const ushort* __restrict__ wp,
    const float* __restrict__ bias, void* __restrict__ out,
    int co_base, const int* __restrict__ flag)
{
  int pt = blockIdx.x;            // px tile: 16 px
  int b  = blockIdx.y;
  int lane = threadIdx.x & 63;
  int w = threadIdx.x >> 6;       // wave -> co group (16 co)
  int n = lane & 15;              // A: m (co); B: n (px); shared index
  int kg = lane >> 4;             // k-group (8 ci each)
  int p0 = pt * 16;
  int y = p0 >> 5, x0 = p0 & 31;

  const ushort* abase = wp + (size_t)(w * 16 + n) * CINT + kg * 8;
  const ushort* bbase = xp + ((size_t)(b * 34 + y) * 34 + x0 + n) * CINT + kg * 8;

  f32x4 acc0 = {0.f, 0.f, 0.f, 0.f};
  f32x4 acc1 = {0.f, 0.f, 0.f, 0.f};
#pragma unroll
  for (int c = 0; c < CINT / 32; c++) {
    int ci0 = c * 32;
#pragma unroll
    for (int kp = 0; kp < 9; kp++) {
      int ky = kp / 3, kx = kp - ky * 3;
      bf16x8 A = *(const bf16x8*)(abase + (size_t)kp * 64 * CINT + ci0);
      bf16x8 B = *(const bf16x8*)(bbase + (size_t)(ky * 34 + kx) * CINT + ci0);
      if (kp & 1) acc1 = __builtin_amdgcn_mfma_f32_16x16x32_bf16(A, B, acc1, 0, 0, 0);
      else        acc0 = __builtin_amdgcn_mfma_f32_16x16x32_bf16(A, B, acc0, 0, 0, 0);
    }
  }

  int f32o = *flag;
#pragma unroll
  for (int r = 0; r < 4; r++) {
    int co = w * 16 + kg * 4 + r;        // D row = (lane>>4)*4 + r
    float v = acc0[r] + acc1[r] + bias[co];
    size_t eoff = ((size_t)b * 128 + co_base + co) * 1024 + p0 + n;   // D col = n
    if (f32o) ((float*)out)[eoff] = v;
    else ((bf16*)out)[eoff] = __float2bfloat16(v);
  }
}

// ---------------------------------------------------------------------------
extern "C" void kernel_launch(void* const* d_in, const int* in_sizes, int n_in,
                              void* d_out, int out_size, void* d_ws, size_t ws_size,
                              hipStream_t stream) {
  float* ws = (float*)d_ws;
  float*  qbuf  = ws + OFF_QBUF;
  ushort* kb16  = (ushort*)(ws + OFF_KB16);
  ushort* vb16  = (ushort*)(ws + OFF_VB16);
  ushort* xpb   = (ushort*)(ws + OFF_XPB);
  ushort* apb   = (ushort*)(ws + OFF_APB);
  ushort* wgb   = (ushort*)(ws + OFF_WGB);
  ushort* wob   = (ushort*)(ws + OFF_WOB);
  float*  bgf   = ws + OFF_BG;
  float*  bqkvf = ws + OFF_BQKV;
  float*  bof   = ws + OFF_BO;
  float*  krhf  = ws + OFF_KRH;
  float*  krwf  = ws + OFF_KRW;
  int*    flag  = (int*)(ws + OFF_FLAG);

  cvt_kernel<<<512, 256, 0, stream>>>(d_in[0], d_in[1], d_in[2], d_in[3], d_in[4],
                                      d_in[5], d_in[6], d_in[7], d_in[8], ws, flag);
  qkv_kernel<<<dim3(8, 16, 6), 256, 0, stream>>>(d_in[0], d_in[3], bqkvf, qbuf, kb16, vb16, flag);
  conv_mfma_kernel<128><<<dim3(64, 8), 256, 0, stream>>>(xpb, wgb, bgf, d_out, 0, flag);
  attn_kernel<<<dim3(16, 8, 8), 256, 0, stream>>>(qbuf, kb16, vb16, krhf, krwf, apb);
  conv_mfma_kernel<64><<<dim3(64, 8), 256, 0, stream>>>(apb, wob, bof, d_out, 64, flag);
}

// Round 13
// 159.551 us; speedup vs baseline: 1.1777x; 1.1777x over previous
//
#include <hip/hip_runtime.h>
#include <hip/hip_bf16.h>

// AAConv2d: B=8, CIN=128, H=W=32, COUT=128, K=3, DK=DV=64, NH=8, dkh=dvh=8
// out[:, 0:64]  = conv3x3(x, w_general) + b_general
// out[:, 64:128]= conv3x3(attn_combined, w_out) + b_out
// Rel logits (verified): logits[n,m] += dot(q[:, m>>5, n>>5], krw[(m&31)-(m>>5)+31])
//                                    + dot(q[:, m>>5, n>>5], krh[(n&31)-(n>>5)+31])
// flat_q/flat_k/flat_v are RAW reshapes: row n = linear elements n*8..n*8+7 of
// the channel-major (8,1024) head block.
// R13: attention QK^T and PV now run on MFMA (16x16x32 bf16, d padded 8->32),
// single-pass upper-bound softmax (no rescale). P round-trips through LDS
// (padded rows) to convert C-layout -> A-layout. V is pre-transposed to
// Vt[16][1024] per head (rows 8-15 zero) by qkv/cvt.

#define NP 1024
#define QSCALE 2.8284271247461903f   // q / (8^-0.5) = q*sqrt(8)
#define LOG2E  1.4426950408889634f

using bf16 = __hip_bfloat16;
typedef unsigned short ushort;
typedef unsigned int uint;
using bf16x8 = __attribute__((ext_vector_type(8))) short;  // 8 bf16 = 4 VGPRs
using f32x4  = __attribute__((ext_vector_type(4))) float;
using f32x2  = __attribute__((ext_vector_type(2))) float;

__device__ __forceinline__ float b2f(bf16 v) { return __bfloat162float(v); }
__device__ __forceinline__ ushort f2b(float v) {
  bf16 h = __float2bfloat16(v);
  ushort u; __builtin_memcpy(&u, &h, 2); return u;
}
__device__ __forceinline__ f32x2 up2(uint u) {   // 2 packed bf16 -> 2 f32
  f32x2 r;
  r[0] = __uint_as_float(u << 16);
  r[1] = __uint_as_float(u & 0xffff0000u);
  return r;
}

__device__ __forceinline__ float dot8(const float* a, const float* b) {
  float s = a[0] * b[0];
  s = fmaf(a[1], b[1], s); s = fmaf(a[2], b[2], s); s = fmaf(a[3], b[3], s);
  s = fmaf(a[4], b[4], s); s = fmaf(a[5], b[5], s); s = fmaf(a[6], b[6], s);
  s = fmaf(a[7], b[7], s);
  return s;
}

__device__ __forceinline__ int fenc(float f) { int i = __float_as_int(f); return i < 0 ? (i ^ 0x7fffffff) : i; }
__device__ __forceinline__ float fdec(int i) { return __int_as_float(i < 0 ? (i ^ 0x7fffffff) : i); }

#if defined(__has_builtin)
#if __has_builtin(__builtin_amdgcn_exp2f)
#define EXP2F __builtin_amdgcn_exp2f
#else
#define EXP2F exp2f
#endif
#else
#define EXP2F exp2f
#endif

// ---- workspace float offsets ----------------------------------------------
#define OFF_QBUF   0          // f32 [8][64][1024]
#define OFF_KB16   524288     // ushort[8][64][1024] raw channel-major bf16
#define OFF_VTB    786432     // ushort[64 heads][16][1024] V^T (rows 8-15 zero)
#define OFF_XPB    1310720    // ushort[8][34][34][128]
#define OFF_APB    1902592    // ushort[8][34][34][64]
#define OFF_WGB    2198528    // ushort[9][64][128]
#define OFF_WOB    2235392    // ushort[9][64][64]
#define OFF_BG     2253824
#define OFF_BQKV   2253888
#define OFF_BO     2254080
#define OFF_KRH    2254144
#define OFF_KRW    2254648
#define OFF_FLAG   2255152

// ---------------------------------------------------------------------------
// Kernel 0: dtype detect + small fp32 copies + halo zeroing + vtb zeroing +
// weight bf16 transforms + (blocks<128) x->xpb bf16 transpose.
// ---------------------------------------------------------------------------
__global__ __launch_bounds__(256) void cvt_kernel(
    const void* __restrict__ p0, const void* __restrict__ p1, const void* __restrict__ p2,
    const void* __restrict__ p3, const void* __restrict__ p4, const void* __restrict__ p5,
    const void* __restrict__ p6, const void* __restrict__ p7, const void* __restrict__ p8,
    float* __restrict__ ws, int* __restrict__ flag)
{
  __shared__ int partial[4];
  __shared__ uint lds[64][65];
  int t = threadIdx.x;
  const unsigned* xraw = (const unsigned*)p0;
  int cnt = 0;
  for (int i = t; i < 1024; i += 256) {
    unsigned elo = (xraw[i] >> 7) & 0xffu;
    cnt += (elo >= 64u && elo <= 133u) ? 1 : 0;
  }
#pragma unroll
  for (int off = 1; off < 64; off <<= 1) cnt += __shfl_xor(cnt, off);
  if ((t & 63) == 0) partial[t >> 6] = cnt;
  __syncthreads();
  int tot = partial[0] + partial[1] + partial[2] + partial[3];
  int f32 = (tot >= 650) ? 0 : 1;   // 1 = fp32 tensors, 0 = bf16 tensors
  if (blockIdx.x == 0 && t == 0) *flag = f32;

  int gsz = gridDim.x * 256;
  int gid = blockIdx.x * 256 + t;

  // small fp32 copies (bg, bqkv, bo, krh, krw)
  const void* src[5] = {p2, p4, p6, p7, p8};
  const int   n[5]    = {64, 192, 64, 504, 504};
  const int   doff[5] = {OFF_BG, OFF_BQKV, OFF_BO, OFF_KRH, OFF_KRW};
#pragma unroll
  for (int s = 0; s < 5; s++) {
    float* dst = ws + doff[s];
    if (f32) { const float* sp = (const float*)src[s];
      for (int i = gid; i < n[s]; i += gsz) dst[i] = sp[i];
    } else { const bf16* sp = (const bf16*)src[s];
      for (int i = gid; i < n[s]; i += gsz) dst[i] = b2f(sp[i]);
    }
  }

  // zero entire vtb (qkv fills rows 0-7 later; rows 8-15 stay zero)
  {
    float4* z = (float4*)(ws + OFF_VTB);
    for (int i = gid; i < 131072; i += gsz) z[i] = float4{0.f, 0.f, 0.f, 0.f};
  }

  // halo zeroing: xpb (16 uint4/px), apb (8 uint4/px)
  {
    uint4 z = {0u, 0u, 0u, 0u};
    uint4* xp = (uint4*)(ws + OFF_XPB);
    uint4* ap = (uint4*)(ws + OFF_APB);
    for (int s = gid; s < 9248; s += gsz) {
      int pb = s / 1156, rem = s - pb * 1156;
      int y = rem / 34, x = rem - y * 34;
      if (y == 0 || y == 33 || x == 0 || x == 33) {
        uint4* d1 = xp + (size_t)s * 16;
#pragma unroll
        for (int k = 0; k < 16; k++) d1[k] = z;
        uint4* d2 = ap + (size_t)s * 8;
#pragma unroll
        for (int k = 0; k < 8; k++) d2[k] = z;
      }
    }
  }

  // w_general -> wgb bf16 [kykx][co][ci]
  {
    ushort* wgb = (ushort*)(ws + OFF_WGB);
    for (int s = gid; s < 73728; s += gsz) {
      int kykx = s >> 13, co = (s >> 7) & 63, ci = s & 127;
      int si = (co * 128 + ci) * 9 + kykx;
      wgb[s] = f32 ? f2b(((const float*)p1)[si]) : ((const ushort*)p1)[si];
    }
  }
  // w_out -> wob bf16 [kykx][co][ci]
  {
    ushort* wob = (ushort*)(ws + OFF_WOB);
    for (int s = gid; s < 36864; s += gsz) {
      int kykx = s >> 12, co = (s >> 6) & 63, ci = s & 63;
      int si = (co * 64 + ci) * 9 + kykx;
      wob[s] = f32 ? f2b(((const float*)p5)[si]) : ((const ushort*)p5)[si];
    }
  }

  // x -> xpb interior transpose (blocks 0..127): 64 px x 128 ci per block
  if (blockIdx.x < 128) {
    int w = t >> 6, lane = t & 63;
    int b = blockIdx.x >> 4;
    int pp0 = (blockIdx.x & 15) * 64;
    if (f32) {
      const float* xs = (const float*)p0 + (size_t)b * 131072 + pp0;
#pragma unroll 4
      for (int i = 0; i < 16; i++) {
        int cp = w * 16 + i;
        float v0 = xs[(size_t)(2 * cp) * 1024 + lane];
        float v1 = xs[(size_t)(2 * cp + 1) * 1024 + lane];
        lds[cp][lane] = (uint)f2b(v0) | ((uint)f2b(v1) << 16);
      }
    } else {
      const ushort* xs = (const ushort*)p0 + (size_t)b * 131072 + pp0;
#pragma unroll 4
      for (int i = 0; i < 16; i++) {
        int cp = w * 16 + i;
        uint v0 = xs[(size_t)(2 * cp) * 1024 + lane];
        uint v1 = xs[(size_t)(2 * cp + 1) * 1024 + lane];
        lds[cp][lane] = v0 | (v1 << 16);
      }
    }
    __syncthreads();
    uint* xp32 = (uint*)(ws + OFF_XPB);
#pragma unroll 4
    for (int i = 0; i < 16; i++) {
      int p = w * 16 + i;
      int pp = pp0 + p;
      int y = pp >> 5, x = pp & 31;
      xp32[((size_t)(b * 34 + y + 1) * 34 + x + 1) * 64 + lane] = lds[lane][p];
    }
  }
}

// ---------------------------------------------------------------------------
// Kernel 1: qkv 1x1 conv. grid (b=8, pg=16, cog=6) = 768 blocks.
// q (cog 0,1): fp32 scaled [b][ch][px]. k (cog 2,3): bf16 RAW channel-major.
// v (cog 4,5): transposed Vt[head][d][m] bf16 (flat_v[m][d] -> [d][m]).
// ---------------------------------------------------------------------------
__global__ __launch_bounds__(256) void qkv_kernel(
    const void* __restrict__ xin, const void* __restrict__ wraw, const float* __restrict__ bias,
    float* __restrict__ qbuf, ushort* __restrict__ kb16, ushort* __restrict__ vtb,
    const int* __restrict__ flag)
{
  __shared__ float xt[128][64];   // 32 KB
  __shared__ float wt[128][36];   // 18 KB
  int b = blockIdx.x, pg = blockIdx.y, cog = blockIdx.z;
  int t = threadIdx.x;
  int p0 = pg * 64;
  int f32 = *flag;
  if (f32) {
    const float* xs = (const float*)xin + (size_t)b * 131072;
    for (int idx = t; idx < 8192; idx += 256) {
      int ci = idx >> 6, p = idx & 63;
      xt[ci][p] = xs[ci * 1024 + p0 + p];
    }
    const float* wsrc = (const float*)wraw;
    for (int idx = t; idx < 4096; idx += 256) {
      int co = idx >> 7, ci = idx & 127;
      wt[ci][co] = wsrc[(cog * 32 + co) * 128 + ci];
    }
  } else {
    const bf16* xs = (const bf16*)xin + (size_t)b * 131072;
    for (int idx = t; idx < 8192; idx += 256) {
      int ci = idx >> 6, p = idx & 63;
      xt[ci][p] = b2f(xs[ci * 1024 + p0 + p]);
    }
    const bf16* wsrc = (const bf16*)wraw;
    for (int idx = t; idx < 4096; idx += 256) {
      int co = idx >> 7, ci = idx & 127;
      wt[ci][co] = b2f(wsrc[(cog * 32 + co) * 128 + ci]);
    }
  }
  __syncthreads();

  int cog2 = t >> 5;        // 0..7 -> 4 co each
  int pl = (t & 31) * 2;    // px pair (even)
  float a0[4] = {0.f, 0.f, 0.f, 0.f};
  float a1[4] = {0.f, 0.f, 0.f, 0.f};
  for (int ci = 0; ci < 128; ci++) {
    float2 xv = *(const float2*)&xt[ci][pl];
    float4 wv = *(const float4*)&wt[ci][cog2 * 4];
    a0[0] = fmaf(xv.x, wv.x, a0[0]); a1[0] = fmaf(xv.y, wv.x, a1[0]);
    a0[1] = fmaf(xv.x, wv.y, a0[1]); a1[1] = fmaf(xv.y, wv.y, a1[1]);
    a0[2] = fmaf(xv.x, wv.z, a0[2]); a1[2] = fmaf(xv.y, wv.z, a1[2]);
    a0[3] = fmaf(xv.x, wv.w, a0[3]); a1[3] = fmaf(xv.y, wv.w, a1[3]);
  }

  if (cog < 2) {
#pragma unroll
    for (int j = 0; j < 4; j++) {
      int co = cog * 32 + cog2 * 4 + j;
      float bv = bias[co];
      float2 pk; pk.x = (a0[j] + bv) * QSCALE; pk.y = (a1[j] + bv) * QSCALE;
      *(float2*)(qbuf + ((size_t)b * 64 + co) * NP + p0 + pl) = pk;
    }
  } else if (cog < 4) {
    uint* dstb = (uint*)kb16;
    int chbase = (cog & 1) * 32;
#pragma unroll
    for (int j = 0; j < 4; j++) {
      int co = cog * 32 + cog2 * 4 + j;
      int ch = chbase + cog2 * 4 + j;
      float bv = bias[co];
      uint u = (uint)f2b(a0[j] + bv) | ((uint)f2b(a1[j] + bv) << 16);
      dstb[(((size_t)b * 64 + ch) * NP + p0 + pl) >> 1] = u;
    }
  } else {
    int chbase = (cog & 1) * 32;
    int px = p0 + pl;                 // even
#pragma unroll
    for (int j = 0; j < 4; j++) {
      int co = cog * 32 + cog2 * 4 + j;
      int ch = chbase + cog2 * 4 + j;
      float bv = bias[co];
      int h = ch >> 3;
      int d0 = px & 7;                          // even, d0+1 <= 7
      int m  = (ch & 7) * 128 + (px >> 3);
      ushort* vt = vtb + ((size_t)(b * 8 + h) * 16 + d0) * 1024 + m;
      vt[0]    = f2b(a0[j] + bv);
      vt[1024] = f2b(a1[j] + bv);
    }
  }
}

// ---------------------------------------------------------------------------
// Kernel 2: MFMA flash attention, single-pass upper-bound softmax (no
// rescale). grid (cp=16, h=8, b=8), 256 thr = 4 waves; wave = 16 q-rows (n),
// m-loop over 1024 in 32-chunks: 2 S-MFMAs (K: d=8 padded to 32, quads 1-3
// zeroed) + bias/exp2 + P->LDS (bf16, padded rows) + 1 PV-MFMA vs Vt.
// C/D layout col=lane&15,row=quad*4+reg and A[m=lane&15][k=quad*8+j] are
// HW-verified by the passing conv_mfma kernels.
// ---------------------------------------------------------------------------
__global__ __launch_bounds__(256, 4) void attn_kernel(
    const float* __restrict__ qbuf, const ushort* __restrict__ kb16, const ushort* __restrict__ vtb,
    const float* __restrict__ krh, const float* __restrict__ krw,
    ushort* __restrict__ apb)
{
  __shared__ float bw2[2][NP];        // 8 KB (scaled by log2e)
  __shared__ float bhT[2][32][32];    // 8 KB (scaled by log2e)
  __shared__ float qsT[2][32][8];     // 2 KB
  __shared__ float krhs[64][8];       // 2 KB
  __shared__ float krws[64][8];       // 2 KB
  __shared__ ushort Plds[4][16][40];  // 5 KB, row stride 40 (bank-safe)
  __shared__ float lred[4][16];
  __shared__ int smax[3];

  int t = threadIdx.x;
  int cp = blockIdx.x, h = blockIdx.y, b = blockIdx.z;
  int C0 = cp * 2;
  const float* qbase = qbuf + ((size_t)b * 64 + h * 8) * NP;
  const uint4* kb4 = (const uint4*)(kb16 + ((size_t)b * 64 + h * 8) * NP);
  const ushort* vth = vtb + (size_t)(b * 8 + h) * 16384;

  if (t < 3) smax[t] = (t == 0) ? 0 : fenc(-3.0e38f);

  for (int idx = t; idx < 63 * 8; idx += 256) {
    krhs[idx >> 3][idx & 7] = krh[idx];
    krws[idx >> 3][idx & 7] = krw[idx];
  }
  for (int idx = t; idx < 512; idx += 256) {
    int cs = idx >> 8, d = (idx >> 5) & 7, r = idx & 31;
    qsT[cs][r][d] = qbase[(size_t)d * NP + r * 32 + (C0 + cs)];
  }
  // scan bf16 flat_k rows for max ||k_m||^2 (same data the MFMA consumes)
  float kn2 = 0.f;
#pragma unroll
  for (int rr = 0; rr < 4; rr++) {
    uint4 ku = kb4[rr * 256 + t];
    f32x2 k0 = up2(ku.x), k1 = up2(ku.y), k2 = up2(ku.z), k3 = up2(ku.w);
    f32x2 s2 = k0 * k0;
    s2 = __builtin_elementwise_fma(k1, k1, s2);
    s2 = __builtin_elementwise_fma(k2, k2, s2);
    s2 = __builtin_elementwise_fma(k3, k3, s2);
    kn2 = fmaxf(kn2, s2[0] + s2[1]);
  }
  __syncthreads();
  atomicMax(&smax[0], __float_as_int(kn2));

  float bwm = -3.0e38f;
  for (int idx = t; idx < 2048; idx += 256) {
    int cs = idx >> 10, m = idx & 1023;
    int rg = m >> 5, j2 = m & 31;
    float s = dot8(qsT[cs][rg], krws[j2 - rg + 31]) * LOG2E;
    bw2[cs][m] = s;
    bwm = fmaxf(bwm, s);
  }
  float bhm = -3.0e38f;
  for (int idx = t; idx < 2048; idx += 256) {
    int cs = idx >> 10, r = idx & 1023;
    int i = r >> 5, J = r & 31;
    float s = dot8(qsT[cs][i], krhs[J - (C0 + cs) + 31]) * LOG2E;
    bhT[cs][i][J] = s;
    bhm = fmaxf(bhm, s);
  }
  atomicMax(&smax[1], fenc(bwm));
  atomicMax(&smax[2], fenc(bhm));
  __syncthreads();

  float kmaxn = sqrtf(__int_as_float(smax[0]));
  float bmax = fdec(smax[1]) + fdec(smax[2]);

  int w = t >> 6, lane = t & 63;
  int quad = lane >> 4, nIdx = lane & 15;
  int n0 = cp * 64 + w * 16;
  int nQ = n0 + nIdx;
  int Cs = w >> 1;
  int J = ((w & 1) << 4) + nIdx;       // n & 31 for this lane's column

  const bf16x8 zero8 = {0, 0, 0, 0, 0, 0, 0, 0};

  // Q B-frag (bf16): quad 0 holds the 8 real d values, others zero.
  // Mn = ||q~|| * kmax + bmax using the bf16-rounded q (exact upper bound).
  const float* qrow = qbase + (size_t)nQ * 8;
  bf16x8 Bq = zero8;
  float nn = 0.f;
  ushort ub[8];
#pragma unroll
  for (int d = 0; d < 8; d++) {
    float v = qrow[d] * LOG2E;
    ub[d] = f2b(v);
    float vr = __uint_as_float((uint)ub[d] << 16);
    nn = fmaf(vr, vr, nn);
  }
  if (quad == 0) {
#pragma unroll
    for (int d = 0; d < 8; d++) Bq[d] = (short)ub[d];
  }
  float Mn = sqrtf(nn) * kmaxn + bmax;

  f32x4 accO = {0.f, 0.f, 0.f, 0.f};
  float lpart = 0.f;
  ushort* prow = &Plds[w][nIdx][0];

#pragma unroll 2
  for (int mc = 0; mc < 32; ++mc) {
    int mb = mc * 32;
    float pre = bhT[Cs][mc][J] - Mn;
    ushort pb[8];
#pragma unroll
    for (int s = 0; s < 2; ++s) {
      int mt = mb + s * 16;
      bf16x8 Ak = *(const bf16x8*)(kb4 + mt + nIdx);   // 16B = flat_k row
      if (quad != 0) Ak = zero8;
      f32x4 S = __builtin_amdgcn_mfma_f32_16x16x32_bf16(Ak, Bq, f32x4{0.f,0.f,0.f,0.f}, 0, 0, 0);
      float4 bw4 = *(const float4*)&bw2[Cs][mt + (quad << 2)];
      const float bwv[4] = {bw4.x, bw4.y, bw4.z, bw4.w};
#pragma unroll
      for (int r = 0; r < 4; ++r) {
        float p = EXP2F(S[r] + bwv[r] + pre);
        lpart += p;
        pb[s * 4 + r] = f2b(p);
      }
    }
    // P -> LDS (C-layout rows m=quad*4+r per tile), then read back A-layout
    uint2 w0, w1;
    w0.x = (uint)pb[0] | ((uint)pb[1] << 16);
    w0.y = (uint)pb[2] | ((uint)pb[3] << 16);
    w1.x = (uint)pb[4] | ((uint)pb[5] << 16);
    w1.y = (uint)pb[6] | ((uint)pb[7] << 16);
    *(uint2*)(prow + (quad << 2))        = w0;
    *(uint2*)(prow + 16 + (quad << 2))   = w1;
    // same-wave LDS: compiler orders via lgkmcnt; no barrier needed
    bf16x8 Ap = *(const bf16x8*)(prow + (quad << 3));
    bf16x8 Bv = *(const bf16x8*)(vth + (size_t)nIdx * 1024 + mb + (quad << 3));
    accO = __builtin_amdgcn_mfma_f32_16x16x32_bf16(Ap, Bv, accO, 0, 0, 0);
  }

  // l: lane has partial for col nIdx over its rows; reduce across quads
  lpart += __shfl_xor(lpart, 16);
  lpart += __shfl_xor(lpart, 32);
  if (lane < 16) lred[w][lane] = lpart;
  float4 lr4 = *(const float4*)&lred[w][quad << 2];
  const float lr[4] = {lr4.x, lr4.y, lr4.z, lr4.w};

  // O: lane holds O[n = n0+quad*4+r][d = nIdx] (d >= 8 lanes discard)
  if (nIdx < 8) {
#pragma unroll
    for (int r = 0; r < 4; ++r) {
      int n = n0 + (quad << 2) + r;
      float v = accO[r] / lr[r];
      apb[((size_t)(b * 34 + (n >> 5) + 1) * 34 + (n & 31) + 1) * 64 + h * 8 + nIdx] = f2b(v);
    }
  }
}

// ---------------------------------------------------------------------------
// Kernel 3: conv3x3 as bf16 MFMA implicit GEMM; dual acc chains.
// grid (pxtile=64, b=8) = 512 blocks.
// ---------------------------------------------------------------------------
template <int CINT>
__global__ __launch_bounds__(256) void conv_mfma_kernel(
    const ushort* __restrict__ xp, const ushort* __restrict__ wp,
    const float* __restrict__ bias, void* __restrict__ out,
    int co_base, const int* __restrict__ flag)
{
  int pt = blockIdx.x;            // px tile: 16 px
  int b  = blockIdx.y;
  int lane = threadIdx.x & 63;
  int w = threadIdx.x >> 6;       // wave -> co group (16 co)
  int n = lane & 15;              // A: m (co); B: n (px); shared index
  int kg = lane >> 4;             // k-group (8 ci each)
  int p0 = pt * 16;
  int y = p0 >> 5, x0 = p0 & 31;

  const ushort* abase = wp + (size_t)(w * 16 + n) * CINT + kg * 8;
  const ushort* bbase = xp + ((size_t)(b * 34 + y) * 34 + x0 + n) * CINT + kg * 8;

  f32x4 acc0 = {0.f, 0.f, 0.f, 0.f};
  f32x4 acc1 = {0.f, 0.f, 0.f, 0.f};
#pragma unroll
  for (int c = 0; c < CINT / 32; c++) {
    int ci0 = c * 32;
#pragma unroll
    for (int kp = 0; kp < 9; kp++) {
      int ky = kp / 3, kx = kp - ky * 3;
      bf16x8 A = *(const bf16x8*)(abase + (size_t)kp * 64 * CINT + ci0);
      bf16x8 B = *(const bf16x8*)(bbase + (size_t)(ky * 34 + kx) * CINT + ci0);
      if (kp & 1) acc1 = __builtin_amdgcn_mfma_f32_16x16x32_bf16(A, B, acc1, 0, 0, 0);
      else        acc0 = __builtin_amdgcn_mfma_f32_16x16x32_bf16(A, B, acc0, 0, 0, 0);
    }
  }

  int f32o = *flag;
#pragma unroll
  for (int r = 0; r < 4; r++) {
    int co = w * 16 + kg * 4 + r;        // D row = (lane>>4)*4 + r
    float v = acc0[r] + acc1[r] + bias[co];
    size_t eoff = ((size_t)b * 128 + co_base + co) * 1024 + p0 + n;   // D col = n
    if (f32o) ((float*)out)[eoff] = v;
    else ((bf16*)out)[eoff] = __float2bfloat16(v);
  }
}

// ---------------------------------------------------------------------------
extern "C" void kernel_launch(void* const* d_in, const int* in_sizes, int n_in,
                              void* d_out, int out_size, void* d_ws, size_t ws_size,
                              hipStream_t stream) {
  float* ws = (float*)d_ws;
  float*  qbuf  = ws + OFF_QBUF;
  ushort* kb16  = (ushort*)(ws + OFF_KB16);
  ushort* vtb   = (ushort*)(ws + OFF_VTB);
  ushort* xpb   = (ushort*)(ws + OFF_XPB);
  ushort* apb   = (ushort*)(ws + OFF_APB);
  ushort* wgb   = (ushort*)(ws + OFF_WGB);
  ushort* wob   = (ushort*)(ws + OFF_WOB);
  float*  bgf   = ws + OFF_BG;
  float*  bqkvf = ws + OFF_BQKV;
  float*  bof   = ws + OFF_BO;
  float*  krhf  = ws + OFF_KRH;
  float*  krwf  = ws + OFF_KRW;
  int*    flag  = (int*)(ws + OFF_FLAG);

  cvt_kernel<<<512, 256, 0, stream>>>(d_in[0], d_in[1], d_in[2], d_in[3], d_in[4],
                                      d_in[5], d_in[6], d_in[7], d_in[8], ws, flag);
  qkv_kernel<<<dim3(8, 16, 6), 256, 0, stream>>>(d_in[0], d_in[3], bqkvf, qbuf, kb16, vtb, flag);
  conv_mfma_kernel<128><<<dim3(64, 8), 256, 0, stream>>>(xpb, wgb, bgf, d_out, 0, flag);
  attn_kernel<<<dim3(16, 8, 8), 256, 0, stream>>>(qbuf, kb16, vtb, krhf, krwf, apb);
  conv_mfma_kernel<64><<<dim3(64, 8), 256, 0, stream>>>(apb, wob, bof, d_out, 64, flag);
}